// Round 7
// baseline (152.419 us; speedup 1.0000x reference)
//
#include <hip/hip_runtime.h>
#include <hip/hip_bf16.h>
#include <cstdint>
#include <cstddef>

#define B_ 8
#define C_ 256
#define N_ 2048
#define H_ 32

typedef __bf16 bf8 __attribute__((ext_vector_type(8)));
typedef float f4 __attribute__((ext_vector_type(4)));
typedef float f16v __attribute__((ext_vector_type(16)));

__device__ inline void gload_lds16(const void* g, void* l) {
  __builtin_amdgcn_global_load_lds(
      (const __attribute__((address_space(1))) unsigned int*)g,
      (__attribute__((address_space(3))) unsigned int*)l, 16, 0, 0);
}

// ---- P1: pack weights: wpk bf16 [320][256] = {wv; wq; wk}, bpk fp32 [320] ----
__global__ __launch_bounds__(256) void pack_kernel(
    const float* __restrict__ wq, const float* __restrict__ wk,
    const float* __restrict__ wv, const float* __restrict__ bq,
    const float* __restrict__ bk, const float* __restrict__ bv,
    __hip_bfloat16* __restrict__ wpk, float* __restrict__ bpk) {
  int r = blockIdx.x, c = threadIdx.x;
  float v;
  if (r < 256)      v = wv[r * 256 + c];
  else if (r < 288) v = wq[(r - 256) * 256 + c];
  else              v = wk[(r - 288) * 256 + c];
  wpk[r * 256 + c] = __float2bfloat16(v);
  if (c == 0) bpk[r] = (r < 256) ? bv[r] : (r < 288 ? bq[r - 256] : bk[r - 288]);
}

// ---- P2: proj GEMM v3: n-tile 16 (grid 1024 = 4 blocks/CU), dbuf staging.
// C[m][n] = sum_c wpk[m][c]*x[b][c][n] + bpk[m].
// m<256 -> vbf[b][m][n]; m>=256 -> qkb[b][n][m-256].
__global__ __launch_bounds__(256) void proj_kernel(
    const float* __restrict__ x, const __hip_bfloat16* __restrict__ wpk,
    const float* __restrict__ bpk, __hip_bfloat16* __restrict__ vbf,
    __hip_bfloat16* __restrict__ qkb) {
  __shared__ __attribute__((aligned(16))) __hip_bfloat16 As[2][320 * 32];  // 40 KB
  int tid = threadIdx.x, wv = tid >> 6, lane = tid & 63;
  int b = blockIdx.y;
  int n0 = blockIdx.x * 16;
  int fcol = lane & 15, hi4 = lane >> 4;          // hi4: k-octet 0..3
  int grow = lane >> 2, gc = (lane & 3) * 8;      // A staging: 16 rows/gload
  const float* xb = x + (size_t)b * C_ * N_;

  // prefetch tile 0 (wpk) + x frag 0 (regs)
#pragma unroll
  for (int g = 0; g < 5; ++g)
    gload_lds16(wpk + (size_t)(wv * 80 + g * 16 + grow) * 256 + gc,
                &As[0][(wv * 80 + g * 16) * 32]);
  float xr[8];
#pragma unroll
  for (int e = 0; e < 8; ++e)
    xr[e] = xb[(size_t)(hi4 * 8 + e) * N_ + n0 + fcol];

  f4 acc[5] = {};
  for (int t = 0; t < 8; ++t) {
    int buf = t & 1;
    __syncthreads();   // drains As[buf] gloads (issued iter t-1) + xr(t) loads
    if (t < 7) {
      int k1 = (t + 1) * 32;
#pragma unroll
      for (int g = 0; g < 5; ++g)
        gload_lds16(wpk + (size_t)(wv * 80 + g * 16 + grow) * 256 + k1 + gc,
                    &As[buf ^ 1][(wv * 80 + g * 16) * 32]);
    }
    bf8 bfr;
#pragma unroll
    for (int e = 0; e < 8; ++e) bfr[e] = (__bf16)xr[e];
    if (t < 7) {
      int k1 = (t + 1) * 32;
#pragma unroll
      for (int e = 0; e < 8; ++e)
        xr[e] = xb[(size_t)(k1 + hi4 * 8 + e) * N_ + n0 + fcol];
    }
#pragma unroll
    for (int s = 0; s < 5; ++s) {
      bf8 af = *(const bf8*)&As[buf][(wv * 80 + s * 16 + fcol) * 32 + hi4 * 8];
      acc[s] = __builtin_amdgcn_mfma_f32_16x16x32_bf16(af, bfr, acc[s], 0, 0, 0);
    }
  }
  int rq = hi4 * 4;
  int n = n0 + fcol;
#pragma unroll
  for (int s = 0; s < 5; ++s)
#pragma unroll
    for (int r = 0; r < 4; ++r) {
      int m = wv * 80 + s * 16 + rq + r;
      float val = acc[s][r] + bpk[m];
      if (m < 256)
        vbf[((size_t)b * C_ + m) * N_ + n] = __float2bfloat16(val);
      else
        qkb[((size_t)b * N_ + n) * 64 + (m - 256)] = __float2bfloat16(val);
    }
}

// ---- fused attention v5: c-tile 64 (grid 1024 = 4 blocks/CU), XCD-pinned b ----
// block: c=64 x i=64. wave (iw=wv>>1, cw=wv&1): acc 32c x 32i; S quadrant
// (iw, jhalf=cw) computed once per wave, shared via pS.
#define FJT 64

__global__ __launch_bounds__(256, 4) void fused_attn(
    const __hip_bfloat16* __restrict__ qk,   // [b][n][64]: q 0..31, k 32..63
    const __hip_bfloat16* __restrict__ vbf,  // [b][c][n]
    const float* __restrict__ x, float* __restrict__ out) {
  __shared__ __attribute__((aligned(16))) __hip_bfloat16 vS[2][64 * FJT];   // 16 KB
  __shared__ __attribute__((aligned(16))) __hip_bfloat16 pS[2][2][32 * 72]; // 18 KB
  __shared__ float lSp[2][2][32];
  int tid = threadIdx.x;
  int wv = tid >> 6, lane = tid & 63;
  int iw = wv >> 1, cw = wv & 1;
  // XCD pinning: b = blk&7 -> all 128 blocks of batch b on one XCD.
  int blk = blockIdx.x;
  int b = blk & 7;
  int rest = blk >> 3;            // 0..127
  int c0 = (rest & 3) * 64;
  int i0 = (rest >> 2) * 64;
  int l31 = lane & 31, hi = lane >> 5;

  const __hip_bfloat16* qkB = qk + (size_t)b * N_ * 64;
  bf8 qf0 = *(const bf8*)&qkB[(size_t)(i0 + iw * 32 + l31) * 64 + hi * 8];
  bf8 qf1 = *(const bf8*)&qkB[(size_t)(i0 + iw * 32 + l31) * 64 + 16 + hi * 8];

  const __hip_bfloat16* vB = vbf + ((size_t)b * C_ + c0) * N_;
  // vS staging: XOR-swizzled 16-B chunks: slot s of row r holds chunk s^(r&7)
  int grow = lane >> 3;
  int gch = ((lane & 7) ^ (grow & 7)) * 8;
  int kjrow = cw * 32 + l31;      // this wave's k rows (j-local half)

  bf8 kf0, kf1, kn0, kn1;
#pragma unroll
  for (int g = 0; g < 2; ++g)
    gload_lds16(vB + (size_t)(wv * 16 + g * 8 + grow) * N_ + gch,
                &vS[0][(wv * 16 + g * 8) * FJT]);
  kf0 = *(const bf8*)&qkB[(size_t)kjrow * 64 + 32 + hi * 8];
  kf1 = *(const bf8*)&qkB[(size_t)kjrow * 64 + 32 + 16 + hi * 8];

  f16v acc0 = {};
  float lp[16];
#pragma unroll
  for (int r = 0; r < 16; ++r) lp[r] = 0.f;

  for (int t = 0; t < N_ / FJT; ++t) {
    int buf = t & 1;
    // S quadrant: 32i x 32j, K=32 via two K=16 MFMAs
    f16v s = {};
    s = __builtin_amdgcn_mfma_f32_32x32x16_bf16(qf0, kf0, s, 0, 0, 0);
    s = __builtin_amdgcn_mfma_f32_32x32x16_bf16(qf1, kf1, s, 0, 0, 0);
    __hip_bfloat16* pW = &pS[buf][iw][0];
#pragma unroll
    for (int r = 0; r < 16; ++r) {
      float p = __expf(s[r]);              // no max-sub: |S| << 88
      lp[r] += p;
      int row = (r & 3) + 8 * (r >> 2) + 4 * hi;
      pW[row * 72 + cw * 32 + l31] = __float2bfloat16(p);
    }
    __syncthreads();   // drains vS[buf] gloads (issued last iter); publishes P[buf]
    if (t + 1 < N_ / FJT) {
      int j1 = (t + 1) * FJT;
#pragma unroll
      for (int g = 0; g < 2; ++g)
        gload_lds16(vB + (size_t)(wv * 16 + g * 8 + grow) * N_ + j1 + gch,
                    &vS[buf ^ 1][(wv * 16 + g * 8) * FJT]);
      kn0 = *(const bf8*)&qkB[(size_t)(j1 + kjrow) * 64 + 32 + hi * 8];
      kn1 = *(const bf8*)&qkB[(size_t)(j1 + kjrow) * 64 + 32 + 16 + hi * 8];
    }
    const __hip_bfloat16* pR = &pS[buf][iw][0];
    int r0 = cw * 32 + l31;     // c-local row 0..63
    int sw = r0 & 7;
#pragma unroll
    for (int jc = 0; jc < 4; ++jc) {
      int ch = jc * 2 + hi;
      bf8 pf = *(const bf8*)&pR[l31 * 72 + jc * 16 + hi * 8];
      bf8 vf = *(const bf8*)&vS[buf][r0 * FJT + ((ch ^ sw) * 8)];
      acc0 = __builtin_amdgcn_mfma_f32_32x32x16_bf16(vf, pf, acc0, 0, 0, 0);
    }
    if (t + 1 < N_ / FJT) { kf0 = kn0; kf1 = kn1; }
  }

  // l: reduce over j-lanes, publish per (iw,cw=jhalf), combine halves
#pragma unroll
  for (int r = 0; r < 16; ++r) {
    float v = lp[r];
    v += __shfl_xor(v, 1); v += __shfl_xor(v, 2); v += __shfl_xor(v, 4);
    v += __shfl_xor(v, 8); v += __shfl_xor(v, 16);
    lp[r] = v;
  }
  if (l31 == 0) {
#pragma unroll
    for (int r = 0; r < 16; ++r)
      lSp[iw][cw][(r & 3) + 8 * (r >> 2) + 4 * hi] = lp[r];
  }
  __syncthreads();
  float linv = 1.0f / (lSp[iw][0][l31] + lSp[iw][1][l31]);
  int i = i0 + iw * 32 + l31;
  const float* xr = x + (size_t)b * C_ * N_;
  float* op = out + (size_t)b * C_ * N_;
#pragma unroll
  for (int r = 0; r < 16; ++r) {
    int row = (r & 3) + 8 * (r >> 2) + 4 * hi;
    size_t o0 = (size_t)(c0 + cw * 32 + row) * N_ + i;
    op[o0] = acc0[r] * linv + xr[o0];
  }
}

extern "C" void kernel_launch(void* const* d_in, const int* in_sizes, int n_in,
                              void* d_out, int out_size, void* d_ws, size_t ws_size,
                              hipStream_t stream) {
  const float* x  = (const float*)d_in[0];
  const float* wq = (const float*)d_in[1];
  const float* bq = (const float*)d_in[2];
  const float* wk = (const float*)d_in[3];
  const float* bk = (const float*)d_in[4];
  const float* wv = (const float*)d_in[5];
  const float* bv = (const float*)d_in[6];
  float* out = (float*)d_out;

  char* ws = (char*)d_ws;
  __hip_bfloat16* qkb = (__hip_bfloat16*)ws;                    // 2 MB [b][n][64]
  __hip_bfloat16* vbf = (__hip_bfloat16*)(ws + (2u << 20));     // 8 MB [b][c][n]
  __hip_bfloat16* wpk = (__hip_bfloat16*)(ws + (10u << 20));    // 160 KB [320][256]
  float*          bpk = (float*)(ws + (10u << 20) + (256u << 10));

  pack_kernel<<<dim3(320), 256, 0, stream>>>(wq, wk, wv, bq, bk, bv, wpk, bpk);
  proj_kernel<<<dim3(N_ / 16, B_), 256, 0, stream>>>(x, wpk, bpk, vbf, qkb);
  fused_attn<<<dim3(1024), 256, 0, stream>>>(qkb, vbf, x, out);
}

// Round 8
// 144.853 us; speedup vs baseline: 1.0522x; 1.0522x over previous
//
#include <hip/hip_runtime.h>
#include <hip/hip_bf16.h>
#include <cstdint>
#include <cstddef>

#define B_ 8
#define C_ 256
#define N_ 2048

typedef __bf16 bf8 __attribute__((ext_vector_type(8)));
typedef float f4 __attribute__((ext_vector_type(4)));
typedef float f16v __attribute__((ext_vector_type(16)));

__device__ inline void gload_lds16(const void* g, void* l) {
  __builtin_amdgcn_global_load_lds(
      (const __attribute__((address_space(1))) unsigned int*)g,
      (__attribute__((address_space(3))) unsigned int*)l, 16, 0, 0);
}

__device__ inline uint32_t pk2(float a, float b) {
  union { __bf16 h[2]; uint32_t u; } cv;
  cv.h[0] = (__bf16)a; cv.h[1] = (__bf16)b; return cv.u;
}
__device__ inline bf8 mk8(uint32_t d0, uint32_t d1, uint32_t d2, uint32_t d3) {
  union { uint32_t u[4]; bf8 v; } cv;
  cv.u[0] = d0; cv.u[1] = d1; cv.u[2] = d2; cv.u[3] = d3; return cv.v;
}

// ---- P1: pack weights: wpk bf16 [320][256] = {wv; wq; wk}, bpk fp32 [320] ----
__global__ __launch_bounds__(256) void pack_kernel(
    const float* __restrict__ wq, const float* __restrict__ wk,
    const float* __restrict__ wv, const float* __restrict__ bq,
    const float* __restrict__ bk, const float* __restrict__ bv,
    __hip_bfloat16* __restrict__ wpk, float* __restrict__ bpk) {
  int r = blockIdx.x, c = threadIdx.x;
  float v;
  if (r < 256)      v = wv[r * 256 + c];
  else if (r < 288) v = wq[(r - 256) * 256 + c];
  else              v = wk[(r - 288) * 256 + c];
  wpk[r * 256 + c] = __float2bfloat16(v);
  if (c == 0) bpk[r] = (r < 256) ? bv[r] : (r < 288 ? bq[r - 256] : bk[r - 288]);
}

// ---- P2: proj GEMM (XCD-pinned, x-loads issued first, qk via LDS transpose)
// C[m][n] = sum_c wpk[m][c]*x[b][c][n] + bpk[m]; m<256 -> vbf, m>=256 -> qkb.
__global__ __launch_bounds__(256) void proj_kernel(
    const float* __restrict__ x, const __hip_bfloat16* __restrict__ wpk,
    const float* __restrict__ bpk, __hip_bfloat16* __restrict__ vbf,
    __hip_bfloat16* __restrict__ qkb) {
  __shared__ __attribute__((aligned(16))) __hip_bfloat16 As[2][320 * 32];  // 40 KB
  __shared__ __attribute__((aligned(16))) __hip_bfloat16 qtr[32 * 72];     // 4.5 KB
  int tid = threadIdx.x, wv = tid >> 6, lane = tid & 63;
  int blk = blockIdx.x;
  int b = blk & 7;                 // XCD pin: writes land in reader's L2
  int n0 = (blk >> 3) * 32;
  int fcol = lane & 15, hi4 = lane >> 4;
  int grow = lane >> 2, gc = (lane & 3) * 8;
  const float* xb = x + (size_t)b * C_ * N_;

#pragma unroll
  for (int g = 0; g < 5; ++g)
    gload_lds16(wpk + (size_t)(wv * 80 + g * 16 + grow) * 256 + gc,
                &As[0][(wv * 80 + g * 16) * 32]);
  float xr[2][2][8];
#pragma unroll
  for (int j = 0; j < 2; ++j)
#pragma unroll
    for (int e = 0; e < 8; ++e)
      xr[0][j][e] = xb[(size_t)(hi4 * 8 + e) * N_ + n0 + j * 16 + fcol];

  f4 acc[5][2] = {};
#pragma unroll 1
  for (int t = 0; t < 8; ++t) {
    int buf = t & 1;
    __syncthreads();               // drains As[buf] DMA + xr[buf] (full iter old)
    if (t < 7) {
      int k1 = (t + 1) * 32;
      // x loads first (HBM latency), then wpk DMA (L2)
#pragma unroll
      for (int j = 0; j < 2; ++j)
#pragma unroll
        for (int e = 0; e < 8; ++e)
          xr[buf ^ 1][j][e] = xb[(size_t)(k1 + hi4 * 8 + e) * N_ + n0 + j * 16 + fcol];
#pragma unroll
      for (int g = 0; g < 5; ++g)
        gload_lds16(wpk + (size_t)(wv * 80 + g * 16 + grow) * 256 + k1 + gc,
                    &As[buf ^ 1][(wv * 80 + g * 16) * 32]);
    }
    bf8 bfr[2];
#pragma unroll
    for (int j = 0; j < 2; ++j)
#pragma unroll
      for (int e = 0; e < 8; ++e) bfr[j][e] = (__bf16)xr[buf][j][e];
#pragma unroll
    for (int s = 0; s < 5; ++s) {
      bf8 af = *(const bf8*)&As[buf][(wv * 80 + s * 16 + fcol) * 32 + hi4 * 8];
      acc[s][0] = __builtin_amdgcn_mfma_f32_16x16x32_bf16(af, bfr[0], acc[s][0], 0, 0, 0);
      acc[s][1] = __builtin_amdgcn_mfma_f32_16x16x32_bf16(af, bfr[1], acc[s][1], 0, 0, 0);
    }
  }
  int rq = hi4 * 4;
#pragma unroll
  for (int s = 0; s < 5; ++s)
#pragma unroll
    for (int r = 0; r < 4; ++r) {
      int m = wv * 80 + s * 16 + rq + r;
      float bias = bpk[m];
#pragma unroll
      for (int j = 0; j < 2; ++j) {
        int nl = j * 16 + fcol;
        float val = acc[s][j][r] + bias;
        if (m < 256)
          vbf[((size_t)b * C_ + m) * N_ + n0 + nl] = __float2bfloat16(val);
        else
          qtr[nl * 72 + (m - 256)] = __float2bfloat16(val);  // wave 3 only
      }
    }
  if (wv == 3) {  // same-wave LDS produce->consume: no barrier needed
#pragma unroll
    for (int p = 0; p < 4; ++p) {
      int nl = lane & 31, oct = (lane >> 5) + p * 2;
      bf8 t8 = *(const bf8*)&qtr[nl * 72 + oct * 8];
      *(bf8*)&qkb[((size_t)b * N_ + n0 + nl) * 64 + oct * 8] = t8;
    }
  }
}

// ---- fused attention v6: barrier-free K-loop, P in registers, v/k from L2 ----
// block c=128 x i=64; 4 waves each own a j-quarter (512 j). End: LDS tree-reduce.
__global__ __launch_bounds__(256, 2) void fused_attn(
    const __hip_bfloat16* __restrict__ qk,   // [b][n][64]: q 0..31, k 32..63
    const __hip_bfloat16* __restrict__ vbf,  // [b][c][n]
    const float* __restrict__ x, float* __restrict__ out) {
  __shared__ float obuf[4 * 128 * 32];       // 64 KB partial-O exchange
  __shared__ float lbuf[4][2][32];
  int tid = threadIdx.x, wv = tid >> 6, lane = tid & 63;
  int blk = blockIdx.x;
  int b = blk & 7;                 // XCD pin
  int rest = blk >> 3;
  int c0 = (rest & 1) * 128;
  int i0 = (rest >> 1) * 64;
  int l31 = lane & 31, hi = lane >> 5;

  const __hip_bfloat16* qkB = qk + (size_t)b * N_ * 64;
  const __hip_bfloat16* vB = vbf + ((size_t)b * C_ + c0) * N_;

  bf8 qf[2][2];
#pragma unroll
  for (int s = 0; s < 2; ++s)
#pragma unroll
    for (int f = 0; f < 2; ++f)
      qf[s][f] = *(const bf8*)&qkB[(size_t)(i0 + s * 32 + l31) * 64 + f * 16 + hi * 8];

  int jg0 = wv * 512;              // this wave's j-quarter
  bf8 kf[2], kn[2];
#pragma unroll
  for (int f = 0; f < 2; ++f)
    kf[f] = *(const bf8*)&qkB[(size_t)(jg0 + l31) * 64 + 32 + f * 16 + hi * 8];

  f16v acc0[4] = {}, acc1[4] = {};
  float lp0 = 0.f, lp1 = 0.f;

#pragma unroll 1
  for (int t = 0; t < 16; ++t) {
    int jg = jg0 + t * 32;
    if (t < 15) {                  // prefetch next k-frag (full iter to land)
#pragma unroll
      for (int f = 0; f < 2; ++f)
        kn[f] = *(const bf8*)&qkB[(size_t)(jg + 32 + l31) * 64 + 32 + f * 16 + hi * 8];
    }
    bf8 vf[4][2];
#pragma unroll
    for (int mt = 0; mt < 2; ++mt)   // first half of v frags issued early
#pragma unroll
      for (int f = 0; f < 2; ++f)
        vf[mt][f] = *(const bf8*)&vB[(size_t)(mt * 32 + l31) * N_ + jg + f * 16 + hi * 8];
    // S^T quadrants: D[m=j][n=i], col=lane&31=i (already B-frag-shaped in n)
    f16v s0 = {}, s1 = {};
    s0 = __builtin_amdgcn_mfma_f32_32x32x16_bf16(kf[0], qf[0][0], s0, 0, 0, 0);
    s0 = __builtin_amdgcn_mfma_f32_32x32x16_bf16(kf[1], qf[0][1], s0, 0, 0, 0);
    s1 = __builtin_amdgcn_mfma_f32_32x32x16_bf16(kf[0], qf[1][0], s1, 0, 0, 0);
    s1 = __builtin_amdgcn_mfma_f32_32x32x16_bf16(kf[1], qf[1][1], s1, 0, 0, 0);
    // exp + pack + cross-half swap -> B-frags (j-octet regroup via lane^32)
    uint32_t pk[8], sw[8];
#pragma unroll
    for (int u = 0; u < 8; ++u) {
      float e0 = __expf(s0[2 * u]), e1 = __expf(s0[2 * u + 1]);  // no max-sub: |S|<<88
      lp0 += e0 + e1;
      pk[u] = pk2(e0, e1);
    }
#pragma unroll
    for (int u = 0; u < 8; ++u) sw[u] = (uint32_t)__shfl_xor((int)pk[u], 32);
    bf8 pf00 = mk8(hi ? sw[2] : pk[0], hi ? sw[3] : pk[1],
                   hi ? pk[2] : sw[0], hi ? pk[3] : sw[1]);
    bf8 pf01 = mk8(hi ? sw[6] : pk[4], hi ? sw[7] : pk[5],
                   hi ? pk[6] : sw[4], hi ? pk[7] : sw[5]);
#pragma unroll
    for (int mt = 2; mt < 4; ++mt)   // second half of v frags
#pragma unroll
      for (int f = 0; f < 2; ++f)
        vf[mt][f] = *(const bf8*)&vB[(size_t)(mt * 32 + l31) * N_ + jg + f * 16 + hi * 8];
#pragma unroll
    for (int u = 0; u < 8; ++u) {
      float e0 = __expf(s1[2 * u]), e1 = __expf(s1[2 * u + 1]);
      lp1 += e0 + e1;
      pk[u] = pk2(e0, e1);
    }
#pragma unroll
    for (int u = 0; u < 8; ++u) sw[u] = (uint32_t)__shfl_xor((int)pk[u], 32);
    bf8 pf10 = mk8(hi ? sw[2] : pk[0], hi ? sw[3] : pk[1],
                   hi ? pk[2] : sw[0], hi ? pk[3] : sw[1]);
    bf8 pf11 = mk8(hi ? sw[6] : pk[4], hi ? sw[7] : pk[5],
                   hi ? pk[6] : sw[4], hi ? pk[7] : sw[5]);
#pragma unroll
    for (int mt = 0; mt < 4; ++mt) {
      acc0[mt] = __builtin_amdgcn_mfma_f32_32x32x16_bf16(vf[mt][0], pf00, acc0[mt], 0, 0, 0);
      acc0[mt] = __builtin_amdgcn_mfma_f32_32x32x16_bf16(vf[mt][1], pf01, acc0[mt], 0, 0, 0);
      acc1[mt] = __builtin_amdgcn_mfma_f32_32x32x16_bf16(vf[mt][0], pf10, acc1[mt], 0, 0, 0);
      acc1[mt] = __builtin_amdgcn_mfma_f32_32x32x16_bf16(vf[mt][1], pf11, acc1[mt], 0, 0, 0);
    }
    kf[0] = kn[0]; kf[1] = kn[1];
  }

  // l: fold lane halves, publish per (wave, isub)
  lp0 += __shfl_xor(lp0, 32);
  lp1 += __shfl_xor(lp1, 32);
  if (hi == 0) { lbuf[wv][0][l31] = lp0; lbuf[wv][1][l31] = lp1; }

  const float* xB = x + (size_t)b * C_ * N_;
  float* oB = out + (size_t)b * C_ * N_;

  // phase 0 (isub0): all waves write partials, then each reduces a c-chunk
#pragma unroll
  for (int mt = 0; mt < 4; ++mt)
#pragma unroll
    for (int r = 0; r < 16; ++r) {
      int row = mt * 32 + (r & 3) + 8 * (r >> 2) + 4 * hi;
      obuf[(wv * 128 + row) * 32 + l31] = acc0[mt][r];
    }
  __syncthreads();
  float linv0 = 1.f / (lbuf[0][0][l31] + lbuf[1][0][l31] + lbuf[2][0][l31] + lbuf[3][0][l31]);
  float linv1 = 1.f / (lbuf[0][1][l31] + lbuf[1][1][l31] + lbuf[2][1][l31] + lbuf[3][1][l31]);
  {
    int ii = i0 + l31;
#pragma unroll
    for (int rr = 0; rr < 16; ++rr) {
      int crow = wv * 32 + hi * 16 + rr;
      float sum = obuf[crow * 32 + l31] + obuf[(128 + crow) * 32 + l31] +
                  obuf[(256 + crow) * 32 + l31] + obuf[(384 + crow) * 32 + l31];
      size_t off = (size_t)(c0 + crow) * N_ + ii;
      oB[off] = sum * linv0 + xB[off];
    }
  }
  __syncthreads();
  // phase 1 (isub1)
#pragma unroll
  for (int mt = 0; mt < 4; ++mt)
#pragma unroll
    for (int r = 0; r < 16; ++r) {
      int row = mt * 32 + (r & 3) + 8 * (r >> 2) + 4 * hi;
      obuf[(wv * 128 + row) * 32 + l31] = acc1[mt][r];
    }
  __syncthreads();
  {
    int ii = i0 + 32 + l31;
#pragma unroll
    for (int rr = 0; rr < 16; ++rr) {
      int crow = wv * 32 + hi * 16 + rr;
      float sum = obuf[crow * 32 + l31] + obuf[(128 + crow) * 32 + l31] +
                  obuf[(256 + crow) * 32 + l31] + obuf[(384 + crow) * 32 + l31];
      size_t off = (size_t)(c0 + crow) * N_ + ii;
      oB[off] = sum * linv1 + xB[off];
    }
  }
}

extern "C" void kernel_launch(void* const* d_in, const int* in_sizes, int n_in,
                              void* d_out, int out_size, void* d_ws, size_t ws_size,
                              hipStream_t stream) {
  const float* x  = (const float*)d_in[0];
  const float* wq = (const float*)d_in[1];
  const float* bq = (const float*)d_in[2];
  const float* wk = (const float*)d_in[3];
  const float* bk = (const float*)d_in[4];
  const float* wv = (const float*)d_in[5];
  const float* bv = (const float*)d_in[6];
  float* out = (float*)d_out;

  char* ws = (char*)d_ws;
  __hip_bfloat16* qkb = (__hip_bfloat16*)ws;                    // 2 MB [b][n][64]
  __hip_bfloat16* vbf = (__hip_bfloat16*)(ws + (2u << 20));     // 8 MB [b][c][n]
  __hip_bfloat16* wpk = (__hip_bfloat16*)(ws + (10u << 20));    // 160 KB [320][256]
  float*          bpk = (float*)(ws + (10u << 20) + (256u << 10));

  pack_kernel<<<dim3(320), 256, 0, stream>>>(wq, wk, wv, bq, bk, bv, wpk, bpk);
  proj_kernel<<<dim3(512), 256, 0, stream>>>(x, wpk, bpk, vbf, qkb);
  fused_attn<<<dim3(512), 256, 0, stream>>>(qkb, vbf, x, out);
}